// Round 10
// baseline (204.389 us; speedup 1.0000x reference)
//
#include <hip/hip_runtime.h>
#include <math.h>

// ---------------------------------------------------------------------------
// SocialLstm: T=24, N=2048, INPUT_DIM=2, HIDDEN=64, MEDIATE=128, SOCIAL=64,
// OUT_DIM=2, N_SIZE=2, CELL=0.3, T_obs=9, T_pred=19, WIN=9.
//
// R10 (on R9's 117us k_persist): LINEARITY SPLIT to break cross-block chains.
//  g = (r,h)*W_rh + e*W_e. Unmatched agents (88%) use const e0*W_e (fp32
//  eW0) -> their LSTM + publish happen right after C1 (r/h tiles), NOT
//  behind the block's own poll. Hop chains across blocks decay ~0.12^k.
//  Step: C1(6kt) -> bar -> P2{unmatched LSTM+early publish || matched
//  poll+edot+e-frag} -> bar -> C2(2kt e-tiles) -> bar -> P3{matched LSTM +
//  publish + out butterfly + t+1 frag build} -> bar.
//  Barriers are lgkmcnt-only (inline asm): no vmcnt(0) store-ack drain on
//  the per-step path (tag protocol self-validates the publishes).
// MFMA hi/lo bf16 split (ZhWh+ZlWh+ZhWl) verified R3-R9, absmax ~2e-3.
// ---------------------------------------------------------------------------

#define N_AG   2048
#define STEPS  20
#define CAP    12

typedef short short8 __attribute__((ext_vector_type(8)));
typedef float f32x4  __attribute__((ext_vector_type(4)));
union FU { uint4 q; short8 v; };

__device__ __forceinline__ unsigned short bf16rne(float x) {
    unsigned u = __float_as_uint(x);
    unsigned r = (u + 0x7fff + ((u >> 16) & 1)) >> 16;
    return (unsigned short)r;
}

__device__ __forceinline__ void pack8(const float* v, uint4& hq, uint4& lq) {
    unsigned uh[4], ul[4];
    #pragma unroll
    for (int w = 0; w < 4; w++) {
        float v0 = v[2 * w], v1 = v[2 * w + 1];
        unsigned short h0 = bf16rne(v0), h1 = bf16rne(v1);
        float f0 = __uint_as_float(((unsigned)h0) << 16);
        float f1 = __uint_as_float(((unsigned)h1) << 16);
        unsigned short l0 = bf16rne(v0 - f0), l1 = bf16rne(v1 - f1);
        uh[w] = (unsigned)h0 | ((unsigned)h1 << 16);
        ul[w] = (unsigned)l0 | ((unsigned)l1 << 16);
    }
    hq = make_uint4(uh[0], uh[1], uh[2], uh[3]);
    lq = make_uint4(ul[0], ul[1], ul[2], ul[3]);
}

__device__ __forceinline__ int khash(int k) {
    return (int)(((unsigned)k * 2654435761u) >> 21);   // 11-bit bucket
}

__device__ __forceinline__ float fsigm(float x) {
    return __builtin_amdgcn_rcpf(1.f + __expf(-x));
}
__device__ __forceinline__ float ftanh(float x) {
    float e = __expf(2.f * x);
    return 1.f - 2.f * __builtin_amdgcn_rcpf(e + 1.f);
}

// LDS-only barrier: order ds ops, DO NOT drain vmcnt (publish/out stores
// stay in flight; their consumers use the self-validating tag protocol).
__device__ __forceinline__ void bar_lds() {
    asm volatile("s_waitcnt lgkmcnt(0)\n\ts_barrier" ::: "memory");
}

// ---------------------------------------------------------------------------
// k_pre: blocks 0..19 = per-step hash match (+ need flags); block 20 = We
// fold; blocks 21..52 = zero out tail frames. (unchanged, verified R6-R9)
// ---------------------------------------------------------------------------
__global__ __launch_bounds__(512) void k_pre(
    const float* __restrict__ X, const float* __restrict__ masks,
    const float* __restrict__ Wsoc,
    float* __restrict__ Wef, int* __restrict__ mcnt, int* __restrict__ midx,
    int* __restrict__ need, float* __restrict__ otail)
{
    const int bx = blockIdx.x, tid = threadIdx.x;

    if (bx >= 21) {
        otail[(bx - 21) * 512 + tid] = 0.f;
        return;
    }
    if (bx == 20) {
        for (int i = tid; i < 4096; i += 512) {
            int s = i >> 6, k = i & 63;
            float a = 0.f;
            #pragma unroll
            for (int w = 0; w < 9; w++) a += Wsoc[s * 576 + w * 64 + k];
            Wef[i] = a;
        }
        return;
    }

    __shared__ int kk[N_AG];
    __shared__ int head[N_AG];
    __shared__ int nxt[N_AG];
    __shared__ float red[512];
    const int t = bx;
    const float* Xt = X + t * N_AG * 2;

    float mnx = 1e30f, mny = 1e30f;
    for (int i = tid; i < N_AG; i += 512) {
        mnx = fminf(mnx, Xt[2 * i]);
        mny = fminf(mny, Xt[2 * i + 1]);
    }
    red[tid] = mnx; __syncthreads();
    for (int s = 256; s > 0; s >>= 1) { if (tid < s) red[tid] = fminf(red[tid], red[tid + s]); __syncthreads(); }
    float ltx = red[0]; __syncthreads();
    red[tid] = mny; __syncthreads();
    for (int s = 256; s > 0; s >>= 1) { if (tid < s) red[tid] = fminf(red[tid], red[tid + s]); __syncthreads(); }
    float lty = red[0]; __syncthreads();
    ltx -= 1.2f;   // margin = 2*N_SIZE*CELL
    lty -= 1.2f;

    for (int i = tid; i < N_AG; i += 512) {
        float m = masks[t * N_AG + i];
        int px = (int)floorf((Xt[2 * i]     - ltx) / 0.3f);
        int py = (int)floorf((Xt[2 * i + 1] - lty) / 0.3f);
        int im = (int)m;
        px *= im; py *= im;
        kk[i] = px * 65536 + py;    // masked -> 0; real agents have px,py >= 4
        head[i] = -1;
        if (t >= 1) need[(t - 1) * N_AG + i] = 0;
    }
    __syncthreads();
    for (int j = tid; j < N_AG; j += 512) {
        int kj = kk[j];
        if (kj != 0) nxt[j] = atomicExch(&head[khash(kj)], j);
    }
    __syncthreads();
    for (int i = tid; i < N_AG; i += 512) {
        int ki = kk[i];
        int cnt = 0;
        int base = (t * N_AG + i) * CAP;
        if (ki != 0) {
            int tkey = ki - 65537;
            int lst[CAP];
            for (int j = head[khash(tkey)]; j >= 0; j = nxt[j]) {
                if (kk[j] == tkey) { if (cnt < CAP) lst[cnt] = j; cnt++; }
            }
            if (cnt > CAP) cnt = CAP;
            for (int a = 1; a < cnt; a++) {           // ascending j = ref sum order
                int v = lst[a]; int b = a - 1;
                while (b >= 0 && lst[b] > v) { lst[b + 1] = lst[b]; b--; }
                lst[b + 1] = v;
            }
            for (int a = 0; a < cnt; a++) {
                midx[base + a] = lst[a];
                if (t >= 1) need[(t - 1) * N_AG + lst[a]] = 1;
            }
        }
        mcnt[t * N_AG + i] = cnt;
    }
}

// ---------------------------------------------------------------------------
struct KP {
    const float *X, *masks, *h_in, *c_in;
    const float *Win, *bin, *bsoc, *Wih, *Whh, *bih, *bhh, *Wout, *bout;
    const float *Wef;
    const int *mcnt, *midx, *need;
    float *out;
    unsigned long long *hist;    // 19 slices x [2048][64] of (tag<<32|f32bits)
};

__global__ __launch_bounds__(512, 2) void k_persist(KP p)
{
    __shared__ __align__(16) uint4 zshq[544];     // frag slot s5*17 + m
    __shared__ __align__(16) uint4 zslq[544];
    __shared__ float gbufA[16][258];              // partial: (r,h)*W + (bias later)
    __shared__ float gbufB[16][258];              // full: + e*W_e
    __shared__ float cvs[16][64];                 // wave-local rows
    __shared__ float hs[16][68];                  // wave-local rows
    __shared__ float sWefP[64 * 65];
    __shared__ float2 sWinP[16 * 17];
    __shared__ float sBinP[16 * 9];
    __shared__ float sX[11][16][2];
    __shared__ float sMask[STEPS][16];
    __shared__ int   sCnt[STEPS][16];
    __shared__ int   sNeed[19][16];
    __shared__ int   sMidx[STEPS][16][CAP];
    __shared__ float sBsoc[64], sBc[256], sWout[128], sBout[2], sEW0[256];
    __shared__ uint4 sE0h[8], sE0l[8];

    const int tid   = threadIdx.x;
    const int bx    = blockIdx.x;
    const int wbase = bx * 16;
    const int wv    = tid >> 6, lane = tid & 63;
    const int mA    = lane & 15, quad = lane >> 4;
    const int nt0   = 2 * wv;
    const int m0    = wv, m1 = wv + 8;            // agents owned by this wave

    // =================== prologue: stashes ===================
    if (tid < 256) {
        sBc[tid] = p.bih[tid] + p.bhh[tid];
        // eW0[g] = sum_k relu(bsoc[k]) * Wc[g][128+k]  (all e-cols live in Wih)
        float acc = 0.f;
        const float* wp = p.Wih + tid * 192 + 128;
        for (int k = 0; k < 64; k++) acc += fmaxf(p.bsoc[k], 0.f) * wp[k];
        sEW0[tid] = acc;
    }
    if (tid < 128) {
        sWout[tid] = p.Wout[tid];
        int c = tid;
        sWinP[(c >> 3) * 17 + (c & 7)] = make_float2(p.Win[2 * c], p.Win[2 * c + 1]);
        sBinP[(c >> 3) * 9 + (c & 7)] = p.bin[c];
    }
    if (tid < 64) sBsoc[tid] = p.bsoc[tid];
    if (tid < 2)  sBout[tid] = p.bout[tid];
    if (tid < 8) {
        float v[8];
        #pragma unroll
        for (int j = 0; j < 8; j++) v[j] = fmaxf(p.bsoc[tid * 8 + j], 0.f);
        pack8(v, sE0h[tid], sE0l[tid]);
    }
    if (tid < 352) { int tt = tid / 32, r = tid % 32;
                     sX[tt][r >> 1][r & 1] = p.X[tt * (N_AG * 2) + (wbase + (r >> 1)) * 2 + (r & 1)]; }
    if (tid < 320) { int tt = tid / 16, m2 = tid % 16;
                     sMask[tt][m2] = p.masks[tt * N_AG + wbase + m2];
                     sCnt[tt][m2]  = p.mcnt[tt * N_AG + wbase + m2]; }
    if (tid < 304) { int s = tid / 16, m2 = tid % 16;
                     sNeed[s][m2] = p.need[s * N_AG + wbase + m2]; }
    for (int i = tid; i < 4096; i += 512) sWefP[(i >> 6) * 65 + (i & 63)] = p.Wef[i];
    for (int i = tid; i < STEPS * 16 * CAP; i += 512) {
        int tt = i / (16 * CAP), r = i % (16 * CAP), m2 = r / CAP, n = r % CAP;
        sMidx[tt][m2][n] = p.midx[(tt * N_AG + wbase + m2) * CAP + n];
    }

    // own h (wave-local LDS rows) + c (registers)
    float c0, c1;
    hs[m0][lane] = p.h_in[(wbase + m0) * 64 + lane];
    hs[m1][lane] = p.h_in[(wbase + m1) * 64 + lane];
    c0 = p.c_in[(wbase + m0) * 64 + lane];
    c1 = p.c_in[(wbase + m1) * 64 + lane];

    // register-resident W fragments (hi/lo split), loaded once
    FU wh[2][8], wl[2][8];
    #pragma unroll
    for (int e = 0; e < 2; e++) {
        int g = (nt0 + e) * 16 + mA;
        #pragma unroll
        for (int kt = 0; kt < 8; kt++) {
            int k0 = kt * 32 + quad * 8;        // 8-run never crosses the 192 boundary
            const float* src = (k0 < 192) ? (p.Wih + g * 192 + k0)
                                          : (p.Whh + g * 64 + (k0 - 192));
            float v[8];
            #pragma unroll
            for (int j = 0; j < 8; j++) v[j] = src[j];
            pack8(v, wh[e][kt].q, wl[e][kt].q);
        }
    }

    float oprev0x = 0.f, oprev0y = 0.f, oprev1x = 0.f, oprev1y = 0.f;

    __syncthreads();   // stashes visible (full barrier once, prologue only)

    // =================== prologue: build frags for t=0 ===================
    {
        if (lane < 32) {
            int a = lane & 1, s5r = lane >> 1;
            int m = a ? m1 : m0;
            float px = sX[0][m][0], py = sX[0][m][1];
            float v[8];
            #pragma unroll
            for (int j = 0; j < 8; j++) {
                float2 w2 = sWinP[s5r * 17 + j];
                v[j] = fmaxf(w2.x * px + w2.y * py + sBinP[s5r * 9 + j], 0.f);
            }
            pack8(v, zshq[s5r * 17 + m], zslq[s5r * 17 + m]);
        } else if (lane < 48) {
            int idx = lane - 32, a = idx & 1, s58 = idx >> 1;
            int m = a ? m1 : m0;
            float v[8];
            #pragma unroll
            for (int j = 0; j < 8; j++) v[j] = hs[m][s58 * 8 + j];
            pack8(v, zshq[(24 + s58) * 17 + m], zslq[(24 + s58) * 17 + m]);
        } else {
            int idx = lane - 48, a = idx & 1, s58 = idx >> 1;
            int m = a ? m1 : m0;
            if (sCnt[0][m] == 0) {
                zshq[(16 + s58) * 17 + m] = sE0h[s58];
                zslq[(16 + s58) * 17 + m] = sE0l[s58];
            }
        }
    }
    bar_lds();   // t=0 r/h/e-const frags visible

    // =================== recurrence: 4 lgkm-only barriers/step ===========
    #pragma unroll 1
    for (int t = 0; t < STEPS; t++) {
        const bool mt0 = sCnt[t][m0] > 0;
        const bool mt1 = sCnt[t][m1] > 0;
        float hn0, hn1;

        // ---- C1: r/h k-tiles {0,1,2,3,6,7} -> partial gbufA ----
        f32x4 a0v = {0.f, 0.f, 0.f, 0.f};
        f32x4 a1v = {0.f, 0.f, 0.f, 0.f};
        #pragma unroll
        for (int u = 0; u < 6; u++) {
            const int kt = (u < 4) ? u : u + 2;
            int fi = (kt * 4 + quad) * 17 + mA;
            FU az, bz;
            az.q = zshq[fi];
            bz.q = zslq[fi];
            a0v = __builtin_amdgcn_mfma_f32_16x16x32_bf16(az.v, wh[0][kt].v, a0v, 0, 0, 0);
            a1v = __builtin_amdgcn_mfma_f32_16x16x32_bf16(az.v, wh[1][kt].v, a1v, 0, 0, 0);
            a0v = __builtin_amdgcn_mfma_f32_16x16x32_bf16(bz.v, wh[0][kt].v, a0v, 0, 0, 0);
            a1v = __builtin_amdgcn_mfma_f32_16x16x32_bf16(bz.v, wh[1][kt].v, a1v, 0, 0, 0);
            a0v = __builtin_amdgcn_mfma_f32_16x16x32_bf16(az.v, wl[0][kt].v, a0v, 0, 0, 0);
            a1v = __builtin_amdgcn_mfma_f32_16x16x32_bf16(az.v, wl[1][kt].v, a1v, 0, 0, 0);
        }
        #pragma unroll
        for (int r = 0; r < 4; r++) {
            int row = quad * 4 + r;
            gbufA[row][nt0 * 16 + mA]       = a0v[r];
            gbufA[row][(nt0 + 1) * 16 + mA] = a1v[r];
        }
        bar_lds();   // barA: gbufA + matched e-frag slots free

        // ---- P2: unmatched early LSTM + publish  ||  matched poll+edot ----
        {
            const int hid = lane;
            unsigned long long* hp = p.hist + (size_t)t * (N_AG * 64);
            const unsigned long long tg = ((unsigned long long)(t + 1)) << 32;
            if (!mt0) {
                float gi = gbufA[m0][hid]       + sBc[hid]       + sEW0[hid];
                float gf = gbufA[m0][64 + hid]  + sBc[64 + hid]  + sEW0[64 + hid];
                float gR = gbufA[m0][128 + hid] + sBc[128 + hid] + sEW0[128 + hid];
                float go = gbufA[m0][192 + hid] + sBc[192 + hid] + sEW0[192 + hid];
                float cn = fsigm(gf) * c0 + fsigm(gi) * ftanh(gR);
                hn0 = fsigm(go) * ftanh(cn);
                c0 = cn;
                if (t <= 18 && sNeed[t][m0])
                    __hip_atomic_store(&hp[(wbase + m0) * 64 + hid],
                                       tg | (unsigned long long)__float_as_uint(hn0),
                                       __ATOMIC_RELAXED, __HIP_MEMORY_SCOPE_AGENT);
            }
            if (!mt1) {
                float gi = gbufA[m1][hid]       + sBc[hid]       + sEW0[hid];
                float gf = gbufA[m1][64 + hid]  + sBc[64 + hid]  + sEW0[64 + hid];
                float gR = gbufA[m1][128 + hid] + sBc[128 + hid] + sEW0[128 + hid];
                float go = gbufA[m1][192 + hid] + sBc[192 + hid] + sEW0[192 + hid];
                float cn = fsigm(gf) * c1 + fsigm(gi) * ftanh(gR);
                hn1 = fsigm(go) * ftanh(cn);
                c1 = cn;
                if (t <= 18 && sNeed[t][m1])
                    __hip_atomic_store(&hp[(wbase + m1) * 64 + hid],
                                       tg | (unsigned long long)__float_as_uint(hn1),
                                       __ATOMIC_RELAXED, __HIP_MEMORY_SCOPE_AGENT);
            }
            // matched owned agents: poll + e-dot + e-frag write
            #pragma unroll
            for (int a = 0; a < 2; a++) {
                int m = a ? m1 : m0;
                int cnt = sCnt[t][m];
                if (cnt > 0) {
                    float cv = 0.f;
                    if (t == 0) {
                        for (int n = 0; n < cnt; n++)
                            cv += p.h_in[sMidx[0][m][n] * 64 + lane];
                    } else {
                        const unsigned long long* hb =
                            p.hist + (size_t)(t - 1) * (N_AG * 64);
                        const unsigned tagw = (unsigned)t;
                        for (int n = 0; n < cnt; n++) {
                            int r = sMidx[t][m][n];
                            unsigned long long wd;
                            do { wd = __hip_atomic_load(&hb[r * 64 + lane],
                                     __ATOMIC_RELAXED, __HIP_MEMORY_SCOPE_AGENT);
                            } while ((unsigned)(wd >> 32) != tagw);
                            cv += __uint_as_float((unsigned)wd);
                        }
                    }
                    cvs[m][lane] = cv;           // wave-local
                    float acc = sBsoc[lane];
                    const float* wp = &sWefP[lane * 65];
                    #pragma unroll 8
                    for (int k = 0; k < 64; k++) acc += cvs[m][k] * wp[k];
                    acc = fmaxf(acc, 0.f);
                    float v[8];
                    #pragma unroll
                    for (int jj = 0; jj < 8; jj++)
                        v[jj] = __shfl(acc, (lane & 7) * 8 + jj, 64);
                    if (lane < 8)
                        pack8(v, zshq[(16 + lane) * 17 + m],
                                 zslq[(16 + lane) * 17 + m]);
                }
            }
        }
        bar_lds();   // barB: matched e-frags visible

        // ---- C2: e k-tiles {4,5} -> full gbufB ----
        #pragma unroll
        for (int kt = 4; kt <= 5; kt++) {
            int fi = (kt * 4 + quad) * 17 + mA;
            FU az, bz;
            az.q = zshq[fi];
            bz.q = zslq[fi];
            a0v = __builtin_amdgcn_mfma_f32_16x16x32_bf16(az.v, wh[0][kt].v, a0v, 0, 0, 0);
            a1v = __builtin_amdgcn_mfma_f32_16x16x32_bf16(az.v, wh[1][kt].v, a1v, 0, 0, 0);
            a0v = __builtin_amdgcn_mfma_f32_16x16x32_bf16(bz.v, wh[0][kt].v, a0v, 0, 0, 0);
            a1v = __builtin_amdgcn_mfma_f32_16x16x32_bf16(bz.v, wh[1][kt].v, a1v, 0, 0, 0);
            a0v = __builtin_amdgcn_mfma_f32_16x16x32_bf16(az.v, wl[0][kt].v, a0v, 0, 0, 0);
            a1v = __builtin_amdgcn_mfma_f32_16x16x32_bf16(az.v, wl[1][kt].v, a1v, 0, 0, 0);
        }
        #pragma unroll
        for (int r = 0; r < 4; r++) {
            int row = quad * 4 + r;
            gbufB[row][nt0 * 16 + mA]       = a0v[r];
            gbufB[row][(nt0 + 1) * 16 + mA] = a1v[r];
        }
        bar_lds();   // barC: gbufB visible

        // ---- P3: matched late LSTM + publish; common epilogue ----
        {
            const int hid = lane;
            unsigned long long* hp = p.hist + (size_t)t * (N_AG * 64);
            const unsigned long long tg = ((unsigned long long)(t + 1)) << 32;
            if (mt0) {
                float gi = gbufB[m0][hid]       + sBc[hid];
                float gf = gbufB[m0][64 + hid]  + sBc[64 + hid];
                float gR = gbufB[m0][128 + hid] + sBc[128 + hid];
                float go = gbufB[m0][192 + hid] + sBc[192 + hid];
                float cn = fsigm(gf) * c0 + fsigm(gi) * ftanh(gR);
                hn0 = fsigm(go) * ftanh(cn);
                c0 = cn;
                if (t <= 18 && sNeed[t][m0])
                    __hip_atomic_store(&hp[(wbase + m0) * 64 + hid],
                                       tg | (unsigned long long)__float_as_uint(hn0),
                                       __ATOMIC_RELAXED, __HIP_MEMORY_SCOPE_AGENT);
            }
            if (mt1) {
                float gi = gbufB[m1][hid]       + sBc[hid];
                float gf = gbufB[m1][64 + hid]  + sBc[64 + hid];
                float gR = gbufB[m1][128 + hid] + sBc[128 + hid];
                float go = gbufB[m1][192 + hid] + sBc[192 + hid];
                float cn = fsigm(gf) * c1 + fsigm(gi) * ftanh(gR);
                hn1 = fsigm(go) * ftanh(cn);
                c1 = cn;
                if (t <= 18 && sNeed[t][m1])
                    __hip_atomic_store(&hp[(wbase + m1) * 64 + hid],
                                       tg | (unsigned long long)__float_as_uint(hn1),
                                       __ATOMIC_RELAXED, __HIP_MEMORY_SCOPE_AGENT);
            }
            hs[m0][hid] = hn0;           // wave-local
            hs[m1][hid] = hn1;

            // out: butterfly (all lanes end with all 4 sums)
            float w0 = sWout[hid], w1 = sWout[64 + hid];
            float p00 = hn0 * w0, p01 = hn0 * w1;
            float p10 = hn1 * w0, p11 = hn1 * w1;
            #pragma unroll
            for (int off = 32; off >= 1; off >>= 1) {
                p00 += __shfl_xor(p00, off);
                p01 += __shfl_xor(p01, off);
                p10 += __shfl_xor(p10, off);
                p11 += __shfl_xor(p11, off);
            }
            float mk0 = sMask[t][m0], mk1 = sMask[t][m1];
            float o00 = (p00 + sBout[0]) * mk0, o01 = (p01 + sBout[1]) * mk0;
            float o10 = (p10 + sBout[0]) * mk1, o11 = (p11 + sBout[1]) * mk1;
            if (lane == 0)
                *(float2*)&p.out[(t * N_AG + wbase + m0) * 2] = make_float2(o00, o01);
            if (lane == 1)
                *(float2*)&p.out[(t * N_AG + wbase + m1) * 2] = make_float2(o10, o11);

            if (t < STEPS - 1) {
                const int tn = t + 1;
                // frag duties (r uses oprev = out[t-1] for tn>=11)
                if (lane < 32) {
                    int a = lane & 1, s5r = lane >> 1;
                    int m = a ? m1 : m0;
                    float px, py;
                    if (tn <= 10) { px = sX[tn][m][0]; py = sX[tn][m][1]; }
                    else          { px = a ? oprev1x : oprev0x;
                                    py = a ? oprev1y : oprev0y; }
                    float v[8];
                    #pragma unroll
                    for (int j = 0; j < 8; j++) {
                        float2 w2 = sWinP[s5r * 17 + j];
                        v[j] = fmaxf(w2.x * px + w2.y * py + sBinP[s5r * 9 + j], 0.f);
                    }
                    pack8(v, zshq[s5r * 17 + m], zslq[s5r * 17 + m]);
                } else if (lane < 48) {
                    int idx = lane - 32, a = idx & 1, s58 = idx >> 1;
                    int m = a ? m1 : m0;
                    float v[8];
                    #pragma unroll
                    for (int j = 0; j < 8; j++) v[j] = hs[m][s58 * 8 + j];
                    pack8(v, zshq[(24 + s58) * 17 + m], zslq[(24 + s58) * 17 + m]);
                } else {
                    int idx = lane - 48, a = idx & 1, s58 = idx >> 1;
                    int m = a ? m1 : m0;
                    if (sCnt[tn][m] == 0) {
                        zshq[(16 + s58) * 17 + m] = sE0h[s58];
                        zslq[(16 + s58) * 17 + m] = sE0l[s58];
                    }
                }
            }
            oprev0x = o00; oprev0y = o01;
            oprev1x = o10; oprev1y = o11;
        }
        bar_lds();   // barD: t+1 frags visible
    }
}

// ---------------------------------------------------------------------------
extern "C" void kernel_launch(void* const* d_in, const int* in_sizes, int n_in,
                              void* d_out, int out_size, void* d_ws, size_t ws_size,
                              hipStream_t stream)
{
    KP kp;
    kp.X     = (const float*)d_in[0];
    kp.masks = (const float*)d_in[1];
    kp.h_in  = (const float*)d_in[2];
    kp.c_in  = (const float*)d_in[3];
    // d_in[4] = Y (unused), d_in[5] = T_obs (=9), d_in[6] = T_pred (=19)
    kp.Win   = (const float*)d_in[7];
    kp.bin   = (const float*)d_in[8];
    const float* Wsoc = (const float*)d_in[9];
    kp.bsoc  = (const float*)d_in[10];
    kp.Wih   = (const float*)d_in[11];
    kp.Whh   = (const float*)d_in[12];
    kp.bih   = (const float*)d_in[13];
    kp.bhh   = (const float*)d_in[14];
    kp.Wout  = (const float*)d_in[15];
    kp.bout  = (const float*)d_in[16];
    kp.out   = (float*)d_out;

    unsigned long long* hist = (unsigned long long*)d_ws;   // 19*2048*64 (8B each)
    float* Wef = (float*)(hist + 19 * N_AG * 64);           // 4096
    int*   need = (int*)(Wef + 4096);                       // 19*2048
    int*   mcnt = need + 19 * N_AG;                         // 20*2048
    int*   midx = mcnt + STEPS * N_AG;                      // 20*2048*CAP

    kp.hist = hist; kp.Wef = Wef; kp.need = need; kp.mcnt = mcnt; kp.midx = midx;

    k_pre<<<53, 512, 0, stream>>>(kp.X, kp.masks, Wsoc, Wef, mcnt, midx, need,
                                  kp.out + 20 * N_AG * 2);

    k_persist<<<128, 512, 0, stream>>>(kp);
}

// Round 11
// 190.045 us; speedup vs baseline: 1.0755x; 1.0755x over previous
//
#include <hip/hip_runtime.h>
#include <math.h>

// ---------------------------------------------------------------------------
// SocialLstm: T=24, N=2048, INPUT_DIM=2, HIDDEN=64, MEDIATE=128, SOCIAL=64,
// OUT_DIM=2, N_SIZE=2, CELL=0.3, T_obs=9, T_pred=19, WIN=9.
//
// R11: single fused launch (149 blocks, all co-resident on 256 CUs).
//  Blocks 0..20 = service: per-step hash match (0..19), We fold (20), and
//  out-tail zeroing, producing tables via agent-scope write-through atomic
//  stores + __syncthreads (vmcnt drain) + tagged MAGIC flag.
//  Blocks 21..148 = persist: R8's proven step structure (fastest measured,
//  101.5us) with (a) table loads moved after a flag-spin that overlaps
//  service work with the persist prologue, and (b) lgkm-only barriers in
//  the step loop (no per-step vmcnt(0) publish/out drain; the tag protocol
//  self-validates all cross-block data).
//  R10's linearity split REVERTED (it regressed: 112 vs R8's 101.5).
// MFMA hi/lo bf16 split (ZhWh+ZlWh+ZhWl) verified R3-R10, absmax ~2e-3.
// ---------------------------------------------------------------------------

#define N_AG   2048
#define STEPS  20
#define CAP    12
#define NSRV   21
#define MAGIC  0x13572468

typedef short short8 __attribute__((ext_vector_type(8)));
typedef float f32x4  __attribute__((ext_vector_type(4)));
union FU { uint4 q; short8 v; };

__device__ __forceinline__ unsigned short bf16rne(float x) {
    unsigned u = __float_as_uint(x);
    unsigned r = (u + 0x7fff + ((u >> 16) & 1)) >> 16;
    return (unsigned short)r;
}

__device__ __forceinline__ int khash(int k) {
    return (int)(((unsigned)k * 2654435761u) >> 21);   // 11-bit bucket
}

__device__ __forceinline__ float fsigm(float x) {
    return __builtin_amdgcn_rcpf(1.f + __expf(-x));
}
__device__ __forceinline__ float ftanh(float x) {
    float e = __expf(2.f * x);
    return 1.f - 2.f * __builtin_amdgcn_rcpf(e + 1.f);
}

// LDS-only barrier: orders ds ops block-wide; does NOT drain vmcnt (global
// publish/out stores stay in flight; the tag protocol covers consumers).
__device__ __forceinline__ void bar_lds() {
    asm volatile("s_waitcnt lgkmcnt(0)\n\ts_barrier" ::: "memory");
}

__device__ __forceinline__ void ast(int* p_, int v) {
    __hip_atomic_store(p_, v, __ATOMIC_RELAXED, __HIP_MEMORY_SCOPE_AGENT);
}
__device__ __forceinline__ void astf(float* p_, float v) {
    __hip_atomic_store(p_, v, __ATOMIC_RELAXED, __HIP_MEMORY_SCOPE_AGENT);
}

struct KP {
    const float *X, *masks, *h_in, *c_in;
    const float *Win, *bin, *Wsoc, *bsoc, *Wih, *Whh, *bih, *bhh, *Wout, *bout;
    float *Wef;
    int *mcnt, *midx, *need, *flags;
    float *out;
    unsigned long long *hist;    // 19 slices x [2048][64] of (tag<<32|f32bits)
};

__global__ __launch_bounds__(512, 1) void k_all(KP p)
{
    // ---- persist LDS ----
    __shared__ __align__(16) uint4 zshq[544];     // frag slot s5*17 + m
    __shared__ __align__(16) uint4 zslq[544];
    __shared__ float gbuf[16][258];
    __shared__ float cvs[16][64];
    __shared__ float hs[16][68];
    __shared__ float sWefP[64 * 65];
    __shared__ float2 sWinP[16 * 17];
    __shared__ float sBinP[16 * 9];
    __shared__ float sX[11][16][2];
    __shared__ float sMask[STEPS][16];
    __shared__ int   sCnt[STEPS][16];
    __shared__ int   sNeed[19][16];
    __shared__ int   sMidx[STEPS][16][CAP];
    __shared__ float sBsoc[64], sBc[256], sWout[128], sBout[2];
    __shared__ uint4 sE0h[8], sE0l[8];
    __shared__ float olocal[2][16][2];
    // ---- service LDS ----
    __shared__ int kk[N_AG];
    __shared__ int head[N_AG];
    __shared__ int nxt[N_AG];
    __shared__ float red[512];

    const int tid = threadIdx.x;
    const int bxg = blockIdx.x;

    // =====================================================================
    // SERVICE BLOCKS 0..20
    // =====================================================================
    if (bxg < NSRV) {
        const int sb = bxg;
        // out-tail zero slice (frames 20..23 = 16384 floats over 21 blocks)
        {
            int lo = sb * 780;
            int hi = (sb == NSRV - 1) ? 16384 : lo + 780;
            for (int i = lo + tid; i < hi; i += 512)
                p.out[20 * N_AG * 2 + i] = 0.f;
        }
        if (sb == 20) {           // We fold
            for (int i = tid; i < 4096; i += 512) {
                int s = i >> 6, k = i & 63;
                float a = 0.f;
                #pragma unroll
                for (int w = 0; w < 9; w++) a += p.Wsoc[s * 576 + w * 64 + k];
                astf(&p.Wef[i], a);
            }
            __syncthreads();      // each wave drains vmcnt before the barrier
            if (tid == 0) ast(&p.flags[20], MAGIC);
            return;
        }

        // hash match for step t = sb
        const int t = sb;
        const float* Xt = p.X + t * N_AG * 2;

        float mnx = 1e30f, mny = 1e30f;
        for (int i = tid; i < N_AG; i += 512) {
            mnx = fminf(mnx, Xt[2 * i]);
            mny = fminf(mny, Xt[2 * i + 1]);
        }
        red[tid] = mnx; __syncthreads();
        for (int s = 256; s > 0; s >>= 1) { if (tid < s) red[tid] = fminf(red[tid], red[tid + s]); __syncthreads(); }
        float ltx = red[0]; __syncthreads();
        red[tid] = mny; __syncthreads();
        for (int s = 256; s > 0; s >>= 1) { if (tid < s) red[tid] = fminf(red[tid], red[tid + s]); __syncthreads(); }
        float lty = red[0]; __syncthreads();
        ltx -= 1.2f;   // margin = 2*N_SIZE*CELL
        lty -= 1.2f;

        for (int i = tid; i < N_AG; i += 512) {
            float m = p.masks[t * N_AG + i];
            int px = (int)floorf((Xt[2 * i]     - ltx) / 0.3f);
            int py = (int)floorf((Xt[2 * i + 1] - lty) / 0.3f);
            int im = (int)m;
            px *= im; py *= im;
            kk[i] = px * 65536 + py;    // masked -> 0; real agents px,py >= 4
            head[i] = -1;
            if (t >= 1) ast(&p.need[(t - 1) * N_AG + i], 0);
        }
        __syncthreads();
        for (int j = tid; j < N_AG; j += 512) {
            int kj = kk[j];
            if (kj != 0) nxt[j] = atomicExch(&head[khash(kj)], j);
        }
        __syncthreads();
        for (int i = tid; i < N_AG; i += 512) {
            int ki = kk[i];
            int cnt = 0;
            int base = (t * N_AG + i) * CAP;
            if (ki != 0) {
                int tkey = ki - 65537;
                int lst[CAP];
                for (int j = head[khash(tkey)]; j >= 0; j = nxt[j]) {
                    if (kk[j] == tkey) { if (cnt < CAP) lst[cnt] = j; cnt++; }
                }
                if (cnt > CAP) cnt = CAP;
                for (int a = 1; a < cnt; a++) {       // ascending j = ref order
                    int v = lst[a]; int b = a - 1;
                    while (b >= 0 && lst[b] > v) { lst[b + 1] = lst[b]; b--; }
                    lst[b + 1] = v;
                }
                for (int a = 0; a < cnt; a++) {
                    ast(&p.midx[base + a], lst[a]);
                    if (t >= 1) ast(&p.need[(t - 1) * N_AG + lst[a]], 1);
                }
            }
            ast(&p.mcnt[t * N_AG + i], cnt);
        }
        __syncthreads();          // all waves' table stores acked
        if (tid == 0) ast(&p.flags[t], MAGIC);
        return;
    }

    // =====================================================================
    // PERSIST BLOCKS 21..148  (R8 structure, lgkm-only step barriers)
    // =====================================================================
    const int bx    = bxg - NSRV;
    const int wbase = bx * 16;
    const int wv    = tid >> 6, lane = tid & 63;
    const int mA    = lane & 15, quad = lane >> 4;
    const int nt0   = 2 * wv;

    // ---- prologue part A (independent of service tables) ----
    if (tid < 256) sBc[tid] = p.bih[tid] + p.bhh[tid];
    if (tid < 128) {
        sWout[tid] = p.Wout[tid];
        int c = tid;
        sWinP[(c >> 3) * 17 + (c & 7)] = make_float2(p.Win[2 * c], p.Win[2 * c + 1]);
        sBinP[(c >> 3) * 9 + (c & 7)] = p.bin[c];
    }
    if (tid < 64) sBsoc[tid] = p.bsoc[tid];
    if (tid < 2)  sBout[tid] = p.bout[tid];
    if (tid < 8) {
        unsigned uh[4], ul[4];
        #pragma unroll
        for (int w = 0; w < 4; w++) {
            float v0 = fmaxf(p.bsoc[tid * 8 + 2 * w], 0.f);
            float v1 = fmaxf(p.bsoc[tid * 8 + 2 * w + 1], 0.f);
            unsigned short h0 = bf16rne(v0), h1 = bf16rne(v1);
            float f0 = __uint_as_float(((unsigned)h0) << 16);
            float f1 = __uint_as_float(((unsigned)h1) << 16);
            unsigned short l0 = bf16rne(v0 - f0), l1 = bf16rne(v1 - f1);
            uh[w] = (unsigned)h0 | ((unsigned)h1 << 16);
            ul[w] = (unsigned)l0 | ((unsigned)l1 << 16);
        }
        sE0h[tid] = make_uint4(uh[0], uh[1], uh[2], uh[3]);
        sE0l[tid] = make_uint4(ul[0], ul[1], ul[2], ul[3]);
    }
    if (tid < 352) { int tt = tid / 32, r = tid % 32;
                     sX[tt][r >> 1][r & 1] = p.X[tt * (N_AG * 2) + (wbase + (r >> 1)) * 2 + (r & 1)]; }
    if (tid < 320) { int tt = tid / 16, m2 = tid % 16;
                     sMask[tt][m2] = p.masks[tt * N_AG + wbase + m2]; }

    // own h (LDS) + c (registers)
    float c0, c1;
    {
        int m0 = tid >> 6, h0i = tid & 63, m1 = m0 + 8;
        hs[m0][h0i] = p.h_in[(wbase + m0) * 64 + h0i];
        hs[m1][h0i] = p.h_in[(wbase + m1) * 64 + h0i];
        c0 = p.c_in[(wbase + m0) * 64 + h0i];
        c1 = p.c_in[(wbase + m1) * 64 + h0i];
    }

    // register-resident W fragments (hi/lo split), loaded once
    FU wh[2][8], wl[2][8];
    #pragma unroll
    for (int e = 0; e < 2; e++) {
        int g = (nt0 + e) * 16 + mA;
        #pragma unroll
        for (int kt = 0; kt < 8; kt++) {
            int k0 = kt * 32 + quad * 8;        // 8-run never crosses 192 boundary
            const float* src = (k0 < 192) ? (p.Wih + g * 192 + k0)
                                          : (p.Whh + g * 64 + (k0 - 192));
            unsigned uh[4], ul[4];
            #pragma unroll
            for (int w = 0; w < 4; w++) {
                float a = src[2 * w], b = src[2 * w + 1];
                unsigned short ha = bf16rne(a), hb = bf16rne(b);
                float fa = __uint_as_float(((unsigned)ha) << 16);
                float fb = __uint_as_float(((unsigned)hb) << 16);
                unsigned short la = bf16rne(a - fa), lb = bf16rne(b - fb);
                uh[w] = (unsigned)ha | ((unsigned)hb << 16);
                ul[w] = (unsigned)la | ((unsigned)lb << 16);
            }
            wh[e][kt].q = make_uint4(uh[0], uh[1], uh[2], uh[3]);
            wl[e][kt].q = make_uint4(ul[0], ul[1], ul[2], ul[3]);
        }
    }

    // ---- wait for service flags (overlaps service work with prologue) ----
    if (tid < NSRV) {
        while (__hip_atomic_load(&p.flags[tid], __ATOMIC_RELAXED,
                                 __HIP_MEMORY_SCOPE_AGENT) != MAGIC) { }
    }
    __syncthreads();

    // ---- prologue part B: service tables (first-touch plain loads) ----
    if (tid < 320) { int tt = tid / 16, m2 = tid % 16;
                     sCnt[tt][m2] = p.mcnt[tt * N_AG + wbase + m2]; }
    if (tid < 304) { int s = tid / 16, m2 = tid % 16;
                     sNeed[s][m2] = p.need[s * N_AG + wbase + m2]; }
    for (int i = tid; i < 4096; i += 512) sWefP[(i >> 6) * 65 + (i & 63)] = p.Wef[i];
    for (int i = tid; i < STEPS * 16 * CAP; i += 512) {
        int tt = i / (16 * CAP), r = i % (16 * CAP), m2 = r / CAP, n = r % CAP;
        sMidx[tt][m2][n] = p.midx[(tt * N_AG + wbase + m2) * CAP + n];
    }
    __syncthreads();

    // =================== recurrence (R8 structure) ===================
    #pragma unroll 1
    for (int t = 0; t < STEPS; t++) {
        const int m5 = tid >> 5, s5 = tid & 31;
        const int cnt5 = sCnt[t][m5];

        // ---- B1: r-frags, h-frags, const-e-frags for unmatched ----
        {
            if (s5 < 16) {                       // r-cols c = s5*8 + j
                float px, py;
                if (t <= 10) { px = sX[t][m5][0];         py = sX[t][m5][1]; }
                else         { px = olocal[t & 1][m5][0]; py = olocal[t & 1][m5][1]; }
                float v[8];
                #pragma unroll
                for (int j = 0; j < 8; j++) {
                    float2 w2 = sWinP[s5 * 17 + j];
                    v[j] = fmaxf(w2.x * px + w2.y * py + sBinP[s5 * 9 + j], 0.f);
                }
                unsigned uh[4], ul[4];
                #pragma unroll
                for (int w = 0; w < 4; w++) {
                    float v0 = v[2 * w], v1 = v[2 * w + 1];
                    unsigned short h0 = bf16rne(v0), h1 = bf16rne(v1);
                    float f0 = __uint_as_float(((unsigned)h0) << 16);
                    float f1 = __uint_as_float(((unsigned)h1) << 16);
                    unsigned short l0 = bf16rne(v0 - f0), l1 = bf16rne(v1 - f1);
                    uh[w] = (unsigned)h0 | ((unsigned)h1 << 16);
                    ul[w] = (unsigned)l0 | ((unsigned)l1 << 16);
                }
                zshq[s5 * 17 + m5] = make_uint4(uh[0], uh[1], uh[2], uh[3]);
                zslq[s5 * 17 + m5] = make_uint4(ul[0], ul[1], ul[2], ul[3]);
            } else if (s5 < 24) {                // e-cols: const frag if unmatched
                if (cnt5 == 0) {
                    zshq[s5 * 17 + m5] = sE0h[s5 - 16];
                    zslq[s5 * 17 + m5] = sE0l[s5 - 16];
                }
            } else {                             // h-cols
                float v[8];
                #pragma unroll
                for (int j = 0; j < 8; j++) v[j] = hs[m5][(s5 - 24) * 8 + j];
                unsigned uh[4], ul[4];
                #pragma unroll
                for (int w = 0; w < 4; w++) {
                    float v0 = v[2 * w], v1 = v[2 * w + 1];
                    unsigned short h0 = bf16rne(v0), h1 = bf16rne(v1);
                    float f0 = __uint_as_float(((unsigned)h0) << 16);
                    float f1 = __uint_as_float(((unsigned)h1) << 16);
                    unsigned short l0 = bf16rne(v0 - f0), l1 = bf16rne(v1 - f1);
                    uh[w] = (unsigned)h0 | ((unsigned)h1 << 16);
                    ul[w] = (unsigned)l0 | ((unsigned)l1 << 16);
                }
                zshq[s5 * 17 + m5] = make_uint4(uh[0], uh[1], uh[2], uh[3]);
                zslq[s5 * 17 + m5] = make_uint4(ul[0], ul[1], ul[2], ul[3]);
            }
        }
        bar_lds();   // bar1: r/h/const-e frags visible

        // ---- A'': matched half-waves poll + e-dot + shuffle-frag ----
        if (cnt5 > 0) {
            float a0 = 0.f, a1 = 0.f;
            if (t == 0) {
                for (int n = 0; n < cnt5; n++) {
                    int r = sMidx[0][m5][n];
                    a0 += p.h_in[r * 64 + s5];
                    a1 += p.h_in[r * 64 + s5 + 32];
                }
            } else {
                const unsigned long long* hb = p.hist + (size_t)(t - 1) * (N_AG * 64);
                const unsigned tagw = (unsigned)t;
                for (int n = 0; n < cnt5; n++) {
                    int r = sMidx[t][m5][n];
                    unsigned long long w0, w1;
                    do {
                        w0 = __hip_atomic_load(&hb[r * 64 + s5], __ATOMIC_RELAXED,
                                               __HIP_MEMORY_SCOPE_AGENT);
                        w1 = __hip_atomic_load(&hb[r * 64 + s5 + 32], __ATOMIC_RELAXED,
                                               __HIP_MEMORY_SCOPE_AGENT);
                    } while ((unsigned)(w0 >> 32) != tagw || (unsigned)(w1 >> 32) != tagw);
                    a0 += __uint_as_float((unsigned)w0);
                    a1 += __uint_as_float((unsigned)w1);
                }
            }
            cvs[m5][s5] = a0; cvs[m5][s5 + 32] = a1;
            float acc0 = sBsoc[s5], acc1 = sBsoc[s5 + 32];
            const float* w0p = &sWefP[s5 * 65];
            const float* w1p = &sWefP[(s5 + 32) * 65];
            for (int k = 0; k < 64; k++) {
                float cv = cvs[m5][k];
                acc0 += cv * w0p[k];
                acc1 += cv * w1p[k];
            }
            acc0 = fmaxf(acc0, 0.f);
            acc1 = fmaxf(acc1, 0.f);
            const int base = (m5 & 1) * 32;
            float v[8];
            #pragma unroll
            for (int jj = 0; jj < 8; jj++) {
                int c = s5 * 8 + jj;             // meaningful for s5<8
                int srcl = base + ((c < 32 ? c : c - 32) & 31);
                float va = __shfl(acc0, srcl, 64);
                float vb = __shfl(acc1, srcl, 64);
                v[jj] = (c < 32) ? va : vb;
            }
            if (s5 < 8) {
                unsigned uh[4], ul[4];
                #pragma unroll
                for (int w = 0; w < 4; w++) {
                    float v0 = v[2 * w], v1 = v[2 * w + 1];
                    unsigned short h0 = bf16rne(v0), h1 = bf16rne(v1);
                    float f0 = __uint_as_float(((unsigned)h0) << 16);
                    float f1 = __uint_as_float(((unsigned)h1) << 16);
                    unsigned short l0 = bf16rne(v0 - f0), l1 = bf16rne(v1 - f1);
                    uh[w] = (unsigned)h0 | ((unsigned)h1 << 16);
                    ul[w] = (unsigned)l0 | ((unsigned)l1 << 16);
                }
                zshq[(16 + s5) * 17 + m5] = make_uint4(uh[0], uh[1], uh[2], uh[3]);
                zslq[(16 + s5) * 17 + m5] = make_uint4(ul[0], ul[1], ul[2], ul[3]);
            }
        }

        // ---- C1: r/h k-tiles (0..3, 6, 7) — overlaps other waves' polls ----
        f32x4 a0v = {0.f, 0.f, 0.f, 0.f};
        f32x4 a1v = {0.f, 0.f, 0.f, 0.f};
        #pragma unroll
        for (int u = 0; u < 6; u++) {
            const int kt = (u < 4) ? u : u + 2;   // 0,1,2,3,6,7
            int fi = (kt * 4 + quad) * 17 + mA;
            FU az, bz;
            az.q = zshq[fi];
            bz.q = zslq[fi];
            a0v = __builtin_amdgcn_mfma_f32_16x16x32_bf16(az.v, wh[0][kt].v, a0v, 0, 0, 0);
            a1v = __builtin_amdgcn_mfma_f32_16x16x32_bf16(az.v, wh[1][kt].v, a1v, 0, 0, 0);
            a0v = __builtin_amdgcn_mfma_f32_16x16x32_bf16(bz.v, wh[0][kt].v, a0v, 0, 0, 0);
            a1v = __builtin_amdgcn_mfma_f32_16x16x32_bf16(bz.v, wh[1][kt].v, a1v, 0, 0, 0);
            a0v = __builtin_amdgcn_mfma_f32_16x16x32_bf16(az.v, wl[0][kt].v, a0v, 0, 0, 0);
            a1v = __builtin_amdgcn_mfma_f32_16x16x32_bf16(az.v, wl[1][kt].v, a1v, 0, 0, 0);
        }
        bar_lds();   // bar2: e-frags visible, all C1 issued

        // ---- C2: e k-tiles (4, 5); write gbuf ----
        #pragma unroll
        for (int kt = 4; kt <= 5; kt++) {
            int fi = (kt * 4 + quad) * 17 + mA;
            FU az, bz;
            az.q = zshq[fi];
            bz.q = zslq[fi];
            a0v = __builtin_amdgcn_mfma_f32_16x16x32_bf16(az.v, wh[0][kt].v, a0v, 0, 0, 0);
            a1v = __builtin_amdgcn_mfma_f32_16x16x32_bf16(az.v, wh[1][kt].v, a1v, 0, 0, 0);
            a0v = __builtin_amdgcn_mfma_f32_16x16x32_bf16(bz.v, wh[0][kt].v, a0v, 0, 0, 0);
            a1v = __builtin_amdgcn_mfma_f32_16x16x32_bf16(bz.v, wh[1][kt].v, a1v, 0, 0, 0);
            a0v = __builtin_amdgcn_mfma_f32_16x16x32_bf16(az.v, wl[0][kt].v, a0v, 0, 0, 0);
            a1v = __builtin_amdgcn_mfma_f32_16x16x32_bf16(az.v, wl[1][kt].v, a1v, 0, 0, 0);
        }
        #pragma unroll
        for (int r = 0; r < 4; r++) {
            int row = quad * 4 + r;           // agent slot
            gbuf[row][nt0 * 16 + mA]       = a0v[r];
            gbuf[row][(nt0 + 1) * 16 + mA] = a1v[r];
        }
        bar_lds();   // bar3: gbuf visible

        // ---- D: LSTM; tagged publish of needed h; E: out reduce ----
        {
            int m0 = tid >> 6, hid = tid & 63, m1 = m0 + 8;
            float hn0, hn1;
            {
                float gi = gbuf[m0][hid]       + sBc[hid];
                float gf = gbuf[m0][64 + hid]  + sBc[64 + hid];
                float gR = gbuf[m0][128 + hid] + sBc[128 + hid];
                float go = gbuf[m0][192 + hid] + sBc[192 + hid];
                float cn = fsigm(gf) * c0 + fsigm(gi) * ftanh(gR);
                hn0 = fsigm(go) * ftanh(cn);
                c0 = cn;
                hs[m0][hid] = hn0;
            }
            {
                float gi = gbuf[m1][hid]       + sBc[hid];
                float gf = gbuf[m1][64 + hid]  + sBc[64 + hid];
                float gR = gbuf[m1][128 + hid] + sBc[128 + hid];
                float go = gbuf[m1][192 + hid] + sBc[192 + hid];
                float cn = fsigm(gf) * c1 + fsigm(gi) * ftanh(gR);
                hn1 = fsigm(go) * ftanh(cn);
                c1 = cn;
                hs[m1][hid] = hn1;
            }
            if (t <= 18) {
                unsigned long long* hp = p.hist + (size_t)t * (N_AG * 64);
                unsigned long long tg = ((unsigned long long)(t + 1)) << 32;
                if (sNeed[t][m0])
                    __hip_atomic_store(&hp[(wbase + m0) * 64 + hid],
                                       tg | (unsigned long long)__float_as_uint(hn0),
                                       __ATOMIC_RELAXED, __HIP_MEMORY_SCOPE_AGENT);
                if (sNeed[t][m1])
                    __hip_atomic_store(&hp[(wbase + m1) * 64 + hid],
                                       tg | (unsigned long long)__float_as_uint(hn1),
                                       __ATOMIC_RELAXED, __HIP_MEMORY_SCOPE_AGENT);
            }

            float w0 = sWout[hid], w1 = sWout[64 + hid];
            float p00 = hn0 * w0, p01 = hn0 * w1;
            float p10 = hn1 * w0, p11 = hn1 * w1;
            #pragma unroll
            for (int off = 32; off >= 1; off >>= 1) {
                p00 += __shfl_xor(p00, off);
                p01 += __shfl_xor(p01, off);
                p10 += __shfl_xor(p10, off);
                p11 += __shfl_xor(p11, off);
            }
            if (hid == 0) {
                float mk0 = sMask[t][m0], mk1 = sMask[t][m1];
                float o00 = (p00 + sBout[0]) * mk0, o01 = (p01 + sBout[1]) * mk0;
                float o10 = (p10 + sBout[0]) * mk1, o11 = (p11 + sBout[1]) * mk1;
                p.out[(t * N_AG + wbase + m0) * 2 + 0] = o00;
                p.out[(t * N_AG + wbase + m0) * 2 + 1] = o01;
                p.out[(t * N_AG + wbase + m1) * 2 + 0] = o10;
                p.out[(t * N_AG + wbase + m1) * 2 + 1] = o11;
                olocal[t & 1][m0][0] = o00; olocal[t & 1][m0][1] = o01;
                olocal[t & 1][m1][0] = o10; olocal[t & 1][m1][1] = o11;
            }
        }
        bar_lds();   // bar4: hs + olocal stable before next step
    }
}

// ---------------------------------------------------------------------------
extern "C" void kernel_launch(void* const* d_in, const int* in_sizes, int n_in,
                              void* d_out, int out_size, void* d_ws, size_t ws_size,
                              hipStream_t stream)
{
    KP kp;
    kp.X     = (const float*)d_in[0];
    kp.masks = (const float*)d_in[1];
    kp.h_in  = (const float*)d_in[2];
    kp.c_in  = (const float*)d_in[3];
    // d_in[4] = Y (unused), d_in[5] = T_obs (=9), d_in[6] = T_pred (=19)
    kp.Win   = (const float*)d_in[7];
    kp.bin   = (const float*)d_in[8];
    kp.Wsoc  = (const float*)d_in[9];
    kp.bsoc  = (const float*)d_in[10];
    kp.Wih   = (const float*)d_in[11];
    kp.Whh   = (const float*)d_in[12];
    kp.bih   = (const float*)d_in[13];
    kp.bhh   = (const float*)d_in[14];
    kp.Wout  = (const float*)d_in[15];
    kp.bout  = (const float*)d_in[16];
    kp.out   = (float*)d_out;

    unsigned long long* hist = (unsigned long long*)d_ws;   // 19*2048*64 (8B each)
    float* Wef  = (float*)(hist + 19 * N_AG * 64);          // 4096
    int*   need = (int*)(Wef + 4096);                       // 19*2048
    int*   mcnt = need + 19 * N_AG;                         // 20*2048
    int*   midx = mcnt + STEPS * N_AG;                      // 20*2048*CAP
    int*   flags = midx + STEPS * N_AG * CAP;               // 32

    kp.hist = hist; kp.Wef = Wef; kp.need = need; kp.mcnt = mcnt;
    kp.midx = midx; kp.flags = flags;

    k_all<<<NSRV + 128, 512, 0, stream>>>(kp);
}